// Round 6
// baseline (182.477 us; speedup 1.0000x reference)
//
#include <hip/hip_runtime.h>
#include <hip/hip_fp16.h>

typedef _Float16 half_t;
typedef __attribute__((ext_vector_type(8))) _Float16 half8;
typedef __attribute__((ext_vector_type(4))) _Float16 half4;
typedef __attribute__((ext_vector_type(4))) float floatx4;

#define NJ 24
#define IN_DIM 256
#define HID 128
#define OUT_DIM 6
#define BATCH 16384
#define BM 128  // rows per block: 4 waves x 32 rows

// ws layout (half elements): W1 [j][ks8][n128][kk32], W2 [j][ks4][n128][kk32],
// W3 [j][n16pad][k128], then f32 b3 padded to 16.
#define W1_JSTRIDE (8 * 128 * 32)   // 32768 halves = 64KB
#define W2_JSTRIDE (4 * 128 * 32)   // 16384 halves = 32KB
#define W3_JSTRIDE (16 * 128)       // 2048 halves  = 4KB
#define WT1_ELEMS (NJ * W1_JSTRIDE)
#define WT2_ELEMS (NJ * W2_JSTRIDE)
#define WT3_ELEMS (NJ * W3_JSTRIDE)
#define WT2_OFF WT1_ELEMS
#define WT3_OFF (WT1_ELEMS + WT2_ELEMS)
#define B3P_BYTE_OFF ((size_t)(WT1_ELEMS + WT2_ELEMS + WT3_ELEMS) * 2)
#define PREP_TOTAL (WT1_ELEMS + WT2_ELEMS + WT3_ELEMS + NJ * 16)

// ---------------------------------------------------------------------------
// Prep: f32 -> f16, chunk-major transposed layouts (proven R2-R5).
// ---------------------------------------------------------------------------
__global__ void posemlp_prep(const float* __restrict__ W1, const float* __restrict__ W2,
                             const float* __restrict__ W3, const float* __restrict__ b3,
                             half_t* __restrict__ wt, float* __restrict__ b3p) {
    int t = blockIdx.x * 256 + threadIdx.x;
    if (t < WT1_ELEMS) {
        int j = t / W1_JSTRIDE, r = t % W1_JSTRIDE;
        int ks = r / 4096, r2 = r % 4096;
        int n = r2 / 32, kk = r2 % 32, k = ks * 32 + kk;
        wt[t] = (half_t)W1[((size_t)j * IN_DIM + k) * HID + n];
    } else if (t < WT2_OFF + WT2_ELEMS) {
        int u = t - WT2_OFF;
        int j = u / W2_JSTRIDE, r = u % W2_JSTRIDE;
        int ks = r / 4096, r2 = r % 4096;
        int n = r2 / 32, kk = r2 % 32, k = ks * 32 + kk;
        wt[t] = (half_t)W2[((size_t)j * HID + k) * HID + n];
    } else if (t < WT3_OFF + WT3_ELEMS) {
        int u = t - WT3_OFF;
        int j = u / W3_JSTRIDE, r = u % W3_JSTRIDE;
        int n = r / 128, k = r % 128;
        wt[t] = (n < OUT_DIM) ? (half_t)W3[((size_t)j * HID + k) * OUT_DIM + n] : (half_t)0.0f;
    } else if (t < PREP_TOTAL) {
        int u = t - WT3_OFF - WT3_ELEMS;
        int j = u / 16, n = u % 16;
        b3p[u] = (n < OUT_DIM) ? b3[j * OUT_DIM + n] : 0.0f;
    }
}

// ---------------------------------------------------------------------------
// helpers — no barriers, no waitcnt asm; order-pinning clobbers only.
// ---------------------------------------------------------------------------
#define ORDER() asm volatile("" ::: "memory")

// h LDS: [row 0..127][n 0..127] f16, pitch 256B, XOR-swizzled (proven).
__device__ inline half8 lds_read8(const half_t* lds, int r, int k) {
    int byte = r * 256 + k * 2;
    byte ^= (r & 7) << 4;
    return *(const half8*)((const char*)lds + byte);
}
__device__ inline void lds_write4(half_t* lds, int r, int n, half4 v) {
    int byte = r * 256 + n * 2;
    byte ^= (r & 7) << 4;
    *(half4*)((char*)lds + byte) = v;
}

__device__ inline half8 cvt8(floatx4 a, floatx4 b) {
    half8 h;
    h[0] = (_Float16)a[0]; h[1] = (_Float16)a[1]; h[2] = (_Float16)a[2]; h[3] = (_Float16)a[3];
    h[4] = (_Float16)b[0]; h[5] = (_Float16)b[1]; h[6] = (_Float16)b[2]; h[7] = (_Float16)b[3];
    return h;
}

// ---------------------------------------------------------------------------
// Main: 256 threads (4 waves), BM=128, 32 rows/wave (two 16-row groups).
// BARRIER-FREE: weights read directly from L2 (2.4MB f16 fits each XCD L2)
// as per-lane half8 frag loads (contiguous 1KB per wave-instruction); X
// prefetched depth-4 in registers; h is wave-private in LDS (XOR-swizzled).
// Correctness is pure dataflow: compiler-inserted waitcnts + same-wave DS
// ordering. Waves drift freely -> continuous HBM demand.
// ---------------------------------------------------------------------------
__global__ __launch_bounds__(256, 2) void posemlp_main(
    const float* __restrict__ X, const half_t* __restrict__ wt,
    const float* __restrict__ b1, const float* __restrict__ b2,
    const float* __restrict__ b3p, float* __restrict__ out) {
    __shared__ half_t h_lds[BM * HID];  // 32KB, h only

    const int bid0 = blockIdx.x;
    const int bid = (bid0 & 7) * 384 + (bid0 >> 3);  // XCD swizzle (3072 = 8*384)
    const int j = bid >> 7;
    const int row0 = (bid & 127) * BM;
    const int tid = threadIdx.x;
    const int w = tid >> 6;
    const int l = tid & 63;
    const int lrow = l & 15;
    const int q = l >> 4;

    // this wave's two 16-row groups
    const int rb = w * 32 + lrow;
    const float* xr0 = X + ((size_t)(row0 + rb) * NJ + j) * IN_DIM + q * 8;
    const float* xr1 = X + ((size_t)(row0 + rb + 16) * NJ + j) * IN_DIM + q * 8;

    const half_t* w1j = wt + (size_t)j * W1_JSTRIDE;
    const half_t* w2j = wt + WT2_OFF + (size_t)j * W2_JSTRIDE;
    const half_t* w3j = wt + WT3_OFF + (size_t)j * W3_JSTRIDE;

    // --- X prefetch: depth 4, chunks 0..3 for both row groups (64 VGPR) ---
    floatx4 px[4][2][2];
#pragma unroll
    for (int c = 0; c < 4; ++c) {
        px[c][0][0] = *(const floatx4*)(xr0 + c * 32);
        px[c][0][1] = *(const floatx4*)(xr0 + c * 32 + 4);
        px[c][1][0] = *(const floatx4*)(xr1 + c * 32);
        px[c][1][1] = *(const floatx4*)(xr1 + c * 32 + 4);
    }

    // ---------------- Layer 1: K=256, 8 chunks ----------------
    floatx4 acc[8][2] = {};
#pragma unroll
    for (int ks = 0; ks < 8; ++ks) {
        // read slot FIRST, then refill with chunk ks+4 (read-then-refill)
        half8 bx0 = cvt8(px[ks & 3][0][0], px[ks & 3][0][1]);
        half8 bx1 = cvt8(px[ks & 3][1][0], px[ks & 3][1][1]);
        if (ks < 4) {
            px[ks & 3][0][0] = *(const floatx4*)(xr0 + (ks + 4) * 32);
            px[ks & 3][0][1] = *(const floatx4*)(xr0 + (ks + 4) * 32 + 4);
            px[ks & 3][1][0] = *(const floatx4*)(xr1 + (ks + 4) * 32);
            px[ks & 3][1][1] = *(const floatx4*)(xr1 + (ks + 4) * 32 + 4);
        }
#pragma unroll
        for (int nf = 0; nf < 8; ++nf) {
            half8 a = *(const half8*)&w1j[ks * 4096 + (nf * 16 + lrow) * 32 + q * 8];
            acc[nf][0] = __builtin_amdgcn_mfma_f32_16x16x32_f16(a, bx0, acc[nf][0], 0, 0, 0);
            acc[nf][1] = __builtin_amdgcn_mfma_f32_16x16x32_f16(a, bx1, acc[nf][1], 0, 0, 0);
        }
    }
    {   // h1 = relu(acc + b1) -> LDS (wave-private rows)
        const float* b1j = b1 + j * HID;
#pragma unroll
        for (int nf = 0; nf < 8; ++nf) {
            floatx4 bb = *(const floatx4*)(b1j + nf * 16 + q * 4);
#pragma unroll
            for (int mf = 0; mf < 2; ++mf) {
                floatx4 v = acc[nf][mf];
                half4 hv;
#pragma unroll
                for (int i = 0; i < 4; ++i) hv[i] = (_Float16)fmaxf(v[i] + bb[i], 0.0f);
                lds_write4(h_lds, w * 32 + mf * 16 + lrow, nf * 16 + q * 4, hv);
            }
        }
    }
    ORDER();

    // ---------------- Layer 2: K=128, 4 chunks ----------------
    floatx4 acc2[8][2] = {};
#pragma unroll
    for (int ks = 0; ks < 4; ++ks) {
        half8 bh0 = lds_read8(h_lds, w * 32 + lrow, ks * 32 + q * 8);
        half8 bh1 = lds_read8(h_lds, w * 32 + 16 + lrow, ks * 32 + q * 8);
#pragma unroll
        for (int nf = 0; nf < 8; ++nf) {
            half8 a = *(const half8*)&w2j[ks * 4096 + (nf * 16 + lrow) * 32 + q * 8];
            acc2[nf][0] = __builtin_amdgcn_mfma_f32_16x16x32_f16(a, bh0, acc2[nf][0], 0, 0, 0);
            acc2[nf][1] = __builtin_amdgcn_mfma_f32_16x16x32_f16(a, bh1, acc2[nf][1], 0, 0, 0);
        }
    }
    ORDER();
    {   // h2 = relu(acc2 + b2) -> LDS (same wave-private rows; DS in-order)
        const float* b2j = b2 + j * HID;
#pragma unroll
        for (int nf = 0; nf < 8; ++nf) {
            floatx4 bb = *(const floatx4*)(b2j + nf * 16 + q * 4);
#pragma unroll
            for (int mf = 0; mf < 2; ++mf) {
                floatx4 v = acc2[nf][mf];
                half4 hv;
#pragma unroll
                for (int i = 0; i < 4; ++i) hv[i] = (_Float16)fmaxf(v[i] + bb[i], 0.0f);
                lds_write4(h_lds, w * 32 + mf * 16 + lrow, nf * 16 + q * 4, hv);
            }
        }
    }
    ORDER();

    // ---------------- Layer 3: N padded to 16, K=128 ----------------
    floatx4 acc3[2] = {};
#pragma unroll
    for (int ks = 0; ks < 4; ++ks) {
        half8 a3 = *(const half8*)&w3j[lrow * 128 + (ks * 4 + q) * 8];
        half8 bh0 = lds_read8(h_lds, w * 32 + lrow, ks * 32 + q * 8);
        half8 bh1 = lds_read8(h_lds, w * 32 + 16 + lrow, ks * 32 + q * 8);
        acc3[0] = __builtin_amdgcn_mfma_f32_16x16x32_f16(a3, bh0, acc3[0], 0, 0, 0);
        acc3[1] = __builtin_amdgcn_mfma_f32_16x16x32_f16(a3, bh1, acc3[1], 0, 0, 0);
    }
    {
        floatx4 bb = *(const floatx4*)(b3p + j * 16 + q * 4);
#pragma unroll
        for (int mf = 0; mf < 2; ++mf) {
            const int orow = row0 + w * 32 + mf * 16 + lrow;
            float* op = out + ((size_t)orow * NJ + j) * OUT_DIM;
            floatx4 v = acc3[mf];
            if (q == 0) {
                float2 s0 = {v[0] + bb[0], v[1] + bb[1]};
                float2 s1 = {v[2] + bb[2], v[3] + bb[3]};
                *(float2*)(op + 0) = s0;
                *(float2*)(op + 2) = s1;
            } else if (q == 1) {
                float2 s = {v[0] + bb[0], v[1] + bb[1]};
                *(float2*)(op + 4) = s;
            }
        }
    }
}

// ---------------------------------------------------------------------------
extern "C" void kernel_launch(void* const* d_in, const int* in_sizes, int n_in,
                              void* d_out, int out_size, void* d_ws, size_t ws_size,
                              hipStream_t stream) {
    const float* X  = (const float*)d_in[0];
    const float* W1 = (const float*)d_in[1];
    const float* b1 = (const float*)d_in[2];
    const float* W2 = (const float*)d_in[3];
    const float* b2 = (const float*)d_in[4];
    const float* W3 = (const float*)d_in[5];
    const float* b3 = (const float*)d_in[6];
    float* out = (float*)d_out;

    half_t* wt = (half_t*)d_ws;
    float* b3p = (float*)((char*)d_ws + B3P_BYTE_OFF);

    int prep_blocks = (PREP_TOTAL + 255) / 256;
    posemlp_prep<<<prep_blocks, 256, 0, stream>>>(W1, W2, W3, b3, wt, b3p);

    int grid = NJ * (BATCH / BM);  // 24 * 128 = 3072
    posemlp_main<<<grid, 256, 0, stream>>>(X, wt, b1, b2, b3p, out);
}

// Round 7
// 116.603 us; speedup vs baseline: 1.5649x; 1.5649x over previous
//
#include <hip/hip_runtime.h>
#include <hip/hip_fp16.h>

typedef _Float16 half_t;
typedef __attribute__((ext_vector_type(8))) _Float16 half8;
typedef __attribute__((ext_vector_type(4))) _Float16 half4;
typedef __attribute__((ext_vector_type(4))) float floatx4;

#define NJ 24
#define IN_DIM 256
#define HID 128
#define OUT_DIM 6
#define BATCH 16384
#define BM 128  // rows per block: 4 waves x 32 rows

// ws layout (half elements): W1 [j][ks8][n128][kk32], W2 [j][ks4][n128][kk32],
// W3 [j][n16pad][k128], then f32 b3 padded to 16.
#define W1_JSTRIDE (8 * 128 * 32)   // 32768 halves = 64KB
#define W2_JSTRIDE (4 * 128 * 32)   // 16384 halves = 32KB
#define W3_JSTRIDE (16 * 128)       // 2048 halves  = 4KB
#define WT1_ELEMS (NJ * W1_JSTRIDE)
#define WT2_ELEMS (NJ * W2_JSTRIDE)
#define WT3_ELEMS (NJ * W3_JSTRIDE)
#define WT2_OFF WT1_ELEMS
#define WT3_OFF (WT1_ELEMS + WT2_ELEMS)
#define B3P_BYTE_OFF ((size_t)(WT1_ELEMS + WT2_ELEMS + WT3_ELEMS) * 2)
#define PREP_TOTAL (WT1_ELEMS + WT2_ELEMS + WT3_ELEMS + NJ * 16)

// ---------------------------------------------------------------------------
// Prep: f32 -> f16, chunk-major transposed layouts (proven R2-R6).
// ---------------------------------------------------------------------------
__global__ void posemlp_prep(const float* __restrict__ W1, const float* __restrict__ W2,
                             const float* __restrict__ W3, const float* __restrict__ b3,
                             half_t* __restrict__ wt, float* __restrict__ b3p) {
    int t = blockIdx.x * 256 + threadIdx.x;
    if (t < WT1_ELEMS) {
        int j = t / W1_JSTRIDE, r = t % W1_JSTRIDE;
        int ks = r / 4096, r2 = r % 4096;
        int n = r2 / 32, kk = r2 % 32, k = ks * 32 + kk;
        wt[t] = (half_t)W1[((size_t)j * IN_DIM + k) * HID + n];
    } else if (t < WT2_OFF + WT2_ELEMS) {
        int u = t - WT2_OFF;
        int j = u / W2_JSTRIDE, r = u % W2_JSTRIDE;
        int ks = r / 4096, r2 = r % 4096;
        int n = r2 / 32, kk = r2 % 32, k = ks * 32 + kk;
        wt[t] = (half_t)W2[((size_t)j * HID + k) * HID + n];
    } else if (t < WT3_OFF + WT3_ELEMS) {
        int u = t - WT3_OFF;
        int j = u / W3_JSTRIDE, r = u % W3_JSTRIDE;
        int n = r / 128, k = r % 128;
        wt[t] = (n < OUT_DIM) ? (half_t)W3[((size_t)j * HID + k) * OUT_DIM + n] : (half_t)0.0f;
    } else if (t < PREP_TOTAL) {
        int u = t - WT3_OFF - WT3_ELEMS;
        int j = u / 16, n = u % 16;
        b3p[u] = (n < OUT_DIM) ? b3[j * OUT_DIM + n] : 0.0f;
    }
}

// ---------------------------------------------------------------------------
// helpers
// ---------------------------------------------------------------------------
__device__ inline void gll16(const void* g, void* l) {
    __builtin_amdgcn_global_load_lds(
        (const __attribute__((address_space(1))) unsigned int*)g,
        (__attribute__((address_space(3))) unsigned int*)l, 16, 0, 0);
}

#define VMWAIT(N) asm volatile("s_waitcnt vmcnt(" #N ")" ::: "memory")
#define LGKM0()                                            \
    do {                                                   \
        asm volatile("s_waitcnt lgkmcnt(0)" ::: "memory"); \
        __builtin_amdgcn_sched_barrier(0);                 \
    } while (0)
#define FENCE()                                 \
    do {                                        \
        asm volatile("" ::: "memory");          \
        __builtin_amdgcn_sched_barrier(0);      \
    } while (0)
__device__ inline void barrier_pinned() {
    __builtin_amdgcn_sched_barrier(0);
    __builtin_amdgcn_s_barrier();
    __builtin_amdgcn_sched_barrier(0);
}

// h LDS: [row 0..127][n 0..127] f16, pitch 256B, XOR-swizzled (proven).
__device__ inline half8 lds_read8(const half_t* lds, int r, int k) {
    int byte = r * 256 + k * 2;
    byte ^= (r & 7) << 4;
    return *(const half8*)((const char*)lds + byte);
}
__device__ inline void lds_write4(half_t* lds, int r, int n, half4 v) {
    int byte = r * 256 + n * 2;
    byte ^= (r & 7) << 4;
    *(half4*)((char*)lds + byte) = v;
}

__device__ inline half8 cvt8(floatx4 a, floatx4 b) {
    half8 h;
    h[0] = (_Float16)a[0]; h[1] = (_Float16)a[1]; h[2] = (_Float16)a[2]; h[3] = (_Float16)a[3];
    h[4] = (_Float16)b[0]; h[5] = (_Float16)b[1]; h[6] = (_Float16)b[2]; h[7] = (_Float16)b[3];
    return h;
}

// ---------------------------------------------------------------------------
// Main: 256 threads (4 waves), BM=128, 32 rows/wave (acc[8][2]) -> each LDS
// A-frag read feeds 2 MFMAs, halving LDS weight-read traffic vs BM=64.
// Weight staging: wbuf[2][16KB] double-buffer, 6 gll16 batches G0-G5, with
// DERIVED counted vmcnt (FIFO retire) so no wait ever drains in-flight X:
//   issue: G0(5) G1(4) X012(12) | A0+r8 | G2(4) | A1+r8 | G3(4) | A2+r4 |
//          G4(4) | A3 | G5(4) | C0 | C1
//   waits: pre-A0 VMWAIT(12)=X012; pre-A2 VMWAIT(12)=r8+G3; pre-A3
//          VMWAIT(8)=r4+G4; pre-C0 VMWAIT(4)=G5; pre-C1 VMWAIT(0).
// X prefetch: depth-3 rotation (slot = ks%3), read-then-refill (R6-proven).
// h is wave-private in LDS -> layer epilogues need no barriers.
// ---------------------------------------------------------------------------
__global__ __launch_bounds__(256, 2) void posemlp_main(
    const float* __restrict__ X, const half_t* __restrict__ wt,
    const float* __restrict__ b1, const float* __restrict__ b2,
    const float* __restrict__ b3p, float* __restrict__ out) {
    __shared__ half_t wbuf[2][8192];   // 2 x 16KB (each = 2 ks-chunks)
    __shared__ half_t w3buf[2048];     // 4KB
    __shared__ half_t h_lds[BM * HID]; // 32KB  -> 68KB total, 2 blocks/CU

    const int bid0 = blockIdx.x;
    const int bid = (bid0 & 7) * 384 + (bid0 >> 3);  // XCD swizzle (3072 = 8*384)
    const int j = bid >> 7;
    const int row0 = (bid & 127) * BM;
    const int tid = threadIdx.x;
    const int w = tid >> 6;
    const int l = tid & 63;
    const int lrow = l & 15;
    const int q = l >> 4;

    // this wave's two 16-row groups
    const int rb = w * 32 + lrow;
    const float* xr0 = X + ((size_t)(row0 + rb) * NJ + j) * IN_DIM + q * 8;
    const float* xr1 = X + ((size_t)(row0 + rb + 16) * NJ + j) * IN_DIM + q * 8;

    const half_t* w1j = wt + (size_t)j * W1_JSTRIDE;
    const half_t* w2j = wt + WT2_OFF + (size_t)j * W2_JSTRIDE;
    const half_t* w3j = wt + WT3_OFF + (size_t)j * W3_JSTRIDE;

    // stage-source index (per lane; XOR pre-swizzle on the 16B source slot)
    const int sn = tid >> 2, ss = tid & 3;
    const int wsrc = sn * 32 + (ss ^ ((sn >> 1) & 3)) * 8;  // halves

// stage 16KB (2 ks-chunks) = 4 gll16 per thread
#define STAGE16K(srcbase, dst) do {                                  \
        gll16((srcbase) + wsrc,        (dst) + w * 512);             \
        gll16((srcbase) + 2048 + wsrc, (dst) + 2048 + w * 512);      \
        gll16((srcbase) + 4096 + wsrc, (dst) + 4096 + w * 512);      \
        gll16((srcbase) + 6144 + wsrc, (dst) + 6144 + w * 512); } while (0)

// one L1 ks-step: read px slot, refill chunk ks+3 (if any), 8 frags, 16 MFMA
#define L1_STEP(ks, wb) do {                                                \
        half8 bx0 = cvt8(px[(ks) % 3][0][0], px[(ks) % 3][0][1]);           \
        half8 bx1 = cvt8(px[(ks) % 3][1][0], px[(ks) % 3][1][1]);           \
        if ((ks) < 5) {                                                     \
            px[(ks) % 3][0][0] = *(const floatx4*)(xr0 + ((ks) + 3) * 32);  \
            px[(ks) % 3][0][1] = *(const floatx4*)(xr0 + ((ks) + 3) * 32 + 4); \
            px[(ks) % 3][1][0] = *(const floatx4*)(xr1 + ((ks) + 3) * 32);  \
            px[(ks) % 3][1][1] = *(const floatx4*)(xr1 + ((ks) + 3) * 32 + 4); \
        }                                                                   \
        _Pragma("unroll")                                                   \
        for (int nf = 0; nf < 8; ++nf) {                                    \
            const int n = nf * 16 + lrow;                                   \
            half8 a = *(const half8*)&(wb)[n * 32 + (q ^ ((n >> 1) & 3)) * 8]; \
            acc[nf][0] = __builtin_amdgcn_mfma_f32_16x16x32_f16(a, bx0, acc[nf][0], 0, 0, 0); \
            acc[nf][1] = __builtin_amdgcn_mfma_f32_16x16x32_f16(a, bx1, acc[nf][1], 0, 0, 0); \
        }                                                                   \
    } while (0)

// one L2 ks-step
#define L2_STEP(ks, wb) do {                                                \
        half8 bh0 = lds_read8(h_lds, w * 32 + lrow,      (ks) * 32 + q * 8); \
        half8 bh1 = lds_read8(h_lds, w * 32 + 16 + lrow, (ks) * 32 + q * 8); \
        _Pragma("unroll")                                                   \
        for (int nf = 0; nf < 8; ++nf) {                                    \
            const int n = nf * 16 + lrow;                                   \
            half8 a = *(const half8*)&(wb)[n * 32 + (q ^ ((n >> 1) & 3)) * 8]; \
            acc2[nf][0] = __builtin_amdgcn_mfma_f32_16x16x32_f16(a, bh0, acc2[nf][0], 0, 0, 0); \
            acc2[nf][1] = __builtin_amdgcn_mfma_f32_16x16x32_f16(a, bh1, acc2[nf][1], 0, 0, 0); \
        }                                                                   \
    } while (0)

    // --- prologue: G0 (W1_0 -> buf0, +w3) G1 (W1_1 -> buf1), then X0-2 ---
    STAGE16K(w1j, wbuf[0]);                       // G0: 4 ops
    {
        const int tn = tid >> 4, tsl = tid & 15;
        gll16(w3j + tn * 128 + (tsl ^ tn) * 8, &w3buf[w * 512]);  // +1
    }
    FENCE();
    STAGE16K(w1j + 8192, wbuf[1]);                // G1: 4 ops
    FENCE();
    floatx4 px[3][2][2];
#pragma unroll
    for (int c = 0; c < 3; ++c) {                 // X0-2: 12 ops
        px[c][0][0] = *(const floatx4*)(xr0 + c * 32);
        px[c][0][1] = *(const floatx4*)(xr0 + c * 32 + 4);
        px[c][1][0] = *(const floatx4*)(xr1 + c * 32);
        px[c][1][1] = *(const floatx4*)(xr1 + c * 32 + 4);
    }
    FENCE();
    VMWAIT(12);            // drain G0,G1; X0-2 stay in flight
    barrier_pinned();

    floatx4 acc[8][2] = {};
    // --- A0: ks 0,1 from buf0 (refills X3,X4: 8 ops) ---
    L1_STEP(0, (&wbuf[0][0]));
    L1_STEP(1, (&wbuf[0][4096]));
    LGKM0();               // this wave's buf0 reads done
    barrier_pinned();      // all waves done with buf0
    STAGE16K(w1j + 16384, wbuf[0]);               // G2: 4 ops
    FENCE();
    // --- A1: ks 2,3 from buf1 (G1 drained at prologue wait; refills X5,X6) ---
    L1_STEP(2, (&wbuf[1][0]));
    L1_STEP(3, (&wbuf[1][4096]));
    LGKM0();
    barrier_pinned();      // buf1 free
    STAGE16K(w1j + 24576, wbuf[1]);               // G3: 4 ops
    FENCE();
    VMWAIT(12);            // drain G2 (newer: r8 + G3 = 12)
    barrier_pinned();
    // --- A2: ks 4,5 from buf0 (refill X7 at ks4: 4 ops) ---
    L1_STEP(4, (&wbuf[0][0]));
    L1_STEP(5, (&wbuf[0][4096]));
    LGKM0();
    barrier_pinned();      // buf0 free
    STAGE16K(w2j, wbuf[0]);                       // G4 (W2_0): 4 ops
    FENCE();
    VMWAIT(8);             // drain G3 (newer: r4 + G4 = 8)
    barrier_pinned();
    // --- A3: ks 6,7 from buf1 ---
    L1_STEP(6, (&wbuf[1][0]));
    L1_STEP(7, (&wbuf[1][4096]));
    {   // h1 = relu(acc + b1) -> LDS (wave-private rows)
        const float* b1j = b1 + j * HID;
#pragma unroll
        for (int nf = 0; nf < 8; ++nf) {
            floatx4 bb = *(const floatx4*)(b1j + nf * 16 + q * 4);
#pragma unroll
            for (int mf = 0; mf < 2; ++mf) {
                floatx4 v = acc[nf][mf];
                half4 hv;
#pragma unroll
                for (int i = 0; i < 4; ++i) hv[i] = (_Float16)fmaxf(v[i] + bb[i], 0.0f);
                lds_write4(h_lds, w * 32 + mf * 16 + lrow, nf * 16 + q * 4, hv);
            }
        }
    }
    LGKM0();
    barrier_pinned();      // buf1 free
    STAGE16K(w2j + 8192, wbuf[1]);                // G5 (W2_1): 4 ops
    FENCE();
    VMWAIT(4);             // drain G4 (newer: G5 = 4)
    barrier_pinned();

    // --- Layer 2: ks 0,1 from buf0 ---
    floatx4 acc2[8][2] = {};
    L2_STEP(0, (&wbuf[0][0]));
    L2_STEP(1, (&wbuf[0][4096]));
    VMWAIT(0);             // drain G5 (buf0 never re-staged; no WAR barrier)
    barrier_pinned();
    // --- Layer 2: ks 2,3 from buf1 ---
    L2_STEP(2, (&wbuf[1][0]));
    L2_STEP(3, (&wbuf[1][4096]));
    {   // h2 = relu(acc2 + b2) -> LDS (same wave-private rows; DS in-order)
        const float* b2j = b2 + j * HID;
#pragma unroll
        for (int nf = 0; nf < 8; ++nf) {
            floatx4 bb = *(const floatx4*)(b2j + nf * 16 + q * 4);
#pragma unroll
            for (int mf = 0; mf < 2; ++mf) {
                floatx4 v = acc2[nf][mf];
                half4 hv;
#pragma unroll
                for (int i = 0; i < 4; ++i) hv[i] = (_Float16)fmaxf(v[i] + bb[i], 0.0f);
                lds_write4(h_lds, w * 32 + mf * 16 + lrow, nf * 16 + q * 4, hv);
            }
        }
    }
    FENCE();

    // --- Layer 3: N padded to 16, K=128 ---
    floatx4 acc3[2] = {};
#pragma unroll
    for (int ks = 0; ks < 4; ++ks) {
        half8 a3 = *(const half8*)&w3buf[lrow * 128 + ((ks * 4 + q) ^ lrow) * 8];
        half8 bh0 = lds_read8(h_lds, w * 32 + lrow, ks * 32 + q * 8);
        half8 bh1 = lds_read8(h_lds, w * 32 + 16 + lrow, ks * 32 + q * 8);
        acc3[0] = __builtin_amdgcn_mfma_f32_16x16x32_f16(a3, bh0, acc3[0], 0, 0, 0);
        acc3[1] = __builtin_amdgcn_mfma_f32_16x16x32_f16(a3, bh1, acc3[1], 0, 0, 0);
    }
    {
        floatx4 bb = *(const floatx4*)(b3p + j * 16 + q * 4);
#pragma unroll
        for (int mf = 0; mf < 2; ++mf) {
            const int orow = row0 + w * 32 + mf * 16 + lrow;
            float* op = out + ((size_t)orow * NJ + j) * OUT_DIM;
            floatx4 v = acc3[mf];
            if (q == 0) {
                float2 s0 = {v[0] + bb[0], v[1] + bb[1]};
                float2 s1 = {v[2] + bb[2], v[3] + bb[3]};
                *(float2*)(op + 0) = s0;
                *(float2*)(op + 2) = s1;
            } else if (q == 1) {
                float2 s = {v[0] + bb[0], v[1] + bb[1]};
                *(float2*)(op + 4) = s;
            }
        }
    }
}

// ---------------------------------------------------------------------------
extern "C" void kernel_launch(void* const* d_in, const int* in_sizes, int n_in,
                              void* d_out, int out_size, void* d_ws, size_t ws_size,
                              hipStream_t stream) {
    const float* X  = (const float*)d_in[0];
    const float* W1 = (const float*)d_in[1];
    const float* b1 = (const float*)d_in[2];
    const float* W2 = (const float*)d_in[3];
    const float* b2 = (const float*)d_in[4];
    const float* W3 = (const float*)d_in[5];
    const float* b3 = (const float*)d_in[6];
    float* out = (float*)d_out;

    half_t* wt = (half_t*)d_ws;
    float* b3p = (float*)((char*)d_ws + B3P_BYTE_OFF);

    int prep_blocks = (PREP_TOTAL + 255) / 256;
    posemlp_prep<<<prep_blocks, 256, 0, stream>>>(W1, W2, W3, b3, wt, b3p);

    int grid = NJ * (BATCH / BM);  // 24 * 128 = 3072
    posemlp_main<<<grid, 256, 0, stream>>>(X, wt, b1, b2, b3p, out);
}